// Round 1
// baseline (113.597 us; speedup 1.0000x reference)
//
#include <hip/hip_runtime.h>

typedef unsigned short u16;
typedef unsigned int u32;
typedef __attribute__((ext_vector_type(8))) short short8;
typedef __attribute__((ext_vector_type(4))) float f32x4;

#define LOG_SQRT_2PI 0.9189385332046727f
#define NB 16
#define NL 512
#define NE 512

__device__ __forceinline__ u16 f2bf(float x) {
    u32 u = __builtin_bit_cast(u32, x);
    u += 0x7fffu + ((u >> 16) & 1u);
    return (u16)(u >> 16);
}

__device__ __forceinline__ void gload_lds16(const u16* g, u16* l) {
    __builtin_amdgcn_global_load_lds(
        (__attribute__((address_space(1))) void*)(u16*)g,
        (__attribute__((address_space(3))) void*)l,
        16, 0, 0);
}

// ---------------- K1: effective taps  cd[3], cn[3], cp[3], cbias ----------------
__global__ void k_taps(const float* __restrict__ wproj,
                       const float* __restrict__ wd, const float* __restrict__ bd,
                       const float* __restrict__ wn, const float* __restrict__ bn,
                       const float* __restrict__ wq, const float* __restrict__ bq,
                       const float* __restrict__ bproj, float* __restrict__ taps) {
    int e = threadIdx.x;  // 512
    float wp = wproj[e];
    float v[10];
    v[0] = wp * wd[e * 3 + 0]; v[1] = wp * wd[e * 3 + 1]; v[2] = wp * wd[e * 3 + 2];
    v[3] = wp * wn[e * 3 + 0]; v[4] = wp * wn[e * 3 + 1]; v[5] = wp * wn[e * 3 + 2];
    v[6] = wp * wq[e * 3 + 0]; v[7] = wp * wq[e * 3 + 1]; v[8] = wp * wq[e * 3 + 2];
    v[9] = wp * (bd[e] + bn[e] + bq[e]);
    __shared__ float red[10][8];
    int lane = threadIdx.x & 63, w = threadIdx.x >> 6;
    #pragma unroll
    for (int i = 0; i < 10; i++) {
        float s = v[i];
        for (int m = 32; m; m >>= 1) s += __shfl_xor(s, m);
        if (lane == 0) red[i][w] = s;
    }
    __syncthreads();
    if (threadIdx.x < 10) {
        float s = 0.f;
        for (int w2 = 0; w2 < 8; w2++) s += red[threadIdx.x][w2];
        if (threadIdx.x == 9) s += bproj[0];
        taps[threadIdx.x] = s;
    }
}

// ---------------- K2: means via inclusive cumsum ----------------
__global__ void k_means(const int* __restrict__ dint, float* __restrict__ means) {
    int b = blockIdx.x, l = threadIdx.x;  // 512 threads
    __shared__ float s[NL];
    float d = (float)dint[b * NL + l];
    s[l] = d;
    __syncthreads();
    for (int off = 1; off < NL; off <<= 1) {
        float v = (l >= off) ? s[l - off] : 0.0f;
        __syncthreads();
        s[l] += v;
        __syncthreads();
    }
    means[b * NL + l] = s[l] - 0.5f * d;
}

// ---------------- K3: ranges -> inv_std, A = -log(std)-C (pad -> -1e30) ----------------
__global__ void k_ranges(const float* __restrict__ x, const float* __restrict__ df,
                         const float* __restrict__ en, const float* __restrict__ pt,
                         const int* __restrict__ lens, const float* __restrict__ taps,
                         const float* __restrict__ wproj,
                         float* __restrict__ inv_std, float* __restrict__ Aarr) {
    int tid = threadIdx.x;                 // 512 threads, 8 waves, wave per (b,l)
    int gl = blockIdx.x * 8 + (tid >> 6);  // 0..8191
    int b = gl >> 9, l = gl & 511;
    int lane = tid & 63;
    const float* xr = x + ((size_t)(b * NL + l)) * NE;
    float4 a0 = *(const float4*)(xr + lane * 4);
    float4 a1 = *(const float4*)(xr + 256 + lane * 4);
    float4 w0 = *(const float4*)(wproj + lane * 4);
    float4 w1 = *(const float4*)(wproj + 256 + lane * 4);
    float dot = a0.x * w0.x + a0.y * w0.y + a0.z * w0.z + a0.w * w0.w
              + a1.x * w1.x + a1.y * w1.y + a1.z * w1.z + a1.w * w1.w;
    for (int m = 32; m; m >>= 1) dot += __shfl_xor(dot, m);
    if (lane == 0) {
        int base = b * NL;
        float dm1 = (l > 0)   ? df[base + l - 1] : 0.f;
        float d0  = df[base + l];
        float dp1 = (l < 511) ? df[base + l + 1] : 0.f;
        float em1 = (l > 0)   ? en[base + l - 1] : 0.f;
        float e0  = en[base + l];
        float ep1 = (l < 511) ? en[base + l + 1] : 0.f;
        float pm1 = (l > 0)   ? pt[base + l - 1] : 0.f;
        float p0  = pt[base + l];
        float pp1 = (l < 511) ? pt[base + l + 1] : 0.f;
        float lin = dot + taps[9]
                  + taps[0] * dm1 + taps[1] * d0 + taps[2] * dp1
                  + taps[3] * em1 + taps[4] * e0 + taps[5] * ep1
                  + taps[6] * pm1 + taps[7] * p0 + taps[8] * pp1;
        float r = (lin > 20.f) ? lin : log1pf(expf(lin));
        bool pad = (l >= lens[b]);
        if (pad) r = 1.0f;
        float sd = fmaxf(r, 0.001f);
        inv_std[base + l] = 1.0f / sd;
        Aarr[base + l] = pad ? -1e30f : (-logf(sd) - LOG_SQRT_2PI);
    }
}

// ---------------- K4: xc = x + conv(nrg) + conv(pitch), transpose -> XcT[b][e][l] bf16 ----------------
__global__ void k_xc(const float* __restrict__ x, const float* __restrict__ en,
                     const float* __restrict__ pt,
                     const float* __restrict__ wn, const float* __restrict__ bn,
                     const float* __restrict__ wq, const float* __restrict__ bq,
                     u16* __restrict__ XcT) {
    __shared__ u16 tile[64][66];
    int b = blockIdx.z;
    int l0 = blockIdx.y * 64, e0 = blockIdx.x * 64;
    int tid = threadIdx.x;         // 256
    int lr = tid >> 6, c = tid & 63;
    int e = e0 + c;
    float wn0 = wn[e * 3], wn1 = wn[e * 3 + 1], wn2 = wn[e * 3 + 2];
    float wq0 = wq[e * 3], wq1 = wq[e * 3 + 1], wq2 = wq[e * 3 + 2];
    float bias = bn[e] + bq[e];
    #pragma unroll 4
    for (int it = 0; it < 16; ++it) {
        int ll = lr * 16 + it;
        int l = l0 + ll;
        int base = b * NL;
        float em1 = (l > 0)   ? en[base + l - 1] : 0.f;
        float ev  = en[base + l];
        float ep1 = (l < 511) ? en[base + l + 1] : 0.f;
        float pm1 = (l > 0)   ? pt[base + l - 1] : 0.f;
        float pv  = pt[base + l];
        float pp1 = (l < 511) ? pt[base + l + 1] : 0.f;
        float v = x[((size_t)(base + l)) * NE + e]
                + wn0 * em1 + wn1 * ev + wn2 * ep1
                + wq0 * pm1 + wq1 * pv + wq2 * pp1 + bias;
        tile[ll][c] = f2bf(v);
    }
    __syncthreads();
    #pragma unroll 4
    for (int it = 0; it < 16; ++it) {
        int eo = lr + 4 * it;  // 0..63
        XcT[((size_t)b * NE + (e0 + eo)) * NL + l0 + c] = tile[c][eo];
    }
}

// ---------------- K5: weights (f32 out) + WtT[b][t][l] bf16, zero-padded rows ----------------
__global__ void k_weights(const float* __restrict__ frames, const float* __restrict__ means,
                          const float* __restrict__ inv_std, const float* __restrict__ Aarr,
                          float* __restrict__ wout, u16* __restrict__ WtT, int T, int Tp) {
    int b = blockIdx.y;
    __shared__ float4 sq[NL];  // {mean, inv_std, A, 0}
    for (int i = threadIdx.x; i < NL; i += 256) {
        sq[i] = make_float4(means[b * NL + i], inv_std[b * NL + i], Aarr[b * NL + i], 0.f);
    }
    __syncthreads();
    int t = blockIdx.x * 256 + threadIdx.x;
    if (t >= Tp) return;
    u16* wrow = WtT + ((size_t)(b * Tp + t)) * NL;
    if (t >= T) {
        uint4 z = make_uint4(0, 0, 0, 0);
        #pragma unroll 4
        for (int i = 0; i < 64; i++) ((uint4*)wrow)[i] = z;
        return;
    }
    float ft = frames[t];
    float sum = 0.f;
    #pragma unroll 4
    for (int l = 0; l < NL; ++l) {
        float4 q = sq[l];
        float z = (ft - q.x) * q.y;
        sum += __expf(fmaf(z, -0.5f * z, q.z));
    }
    float rn = 1.0f / (sum + 1e-20f);
    float* wo = wout + (size_t)b * NL * T + t;
    for (int c = 0; c < 64; c++) {
        u32 pkw[4];
        #pragma unroll
        for (int jj = 0; jj < 4; jj++) {
            int l = c * 8 + jj * 2;
            float4 q0 = sq[l], q1 = sq[l + 1];
            float z0 = (ft - q0.x) * q0.y;
            float p0 = __expf(fmaf(z0, -0.5f * z0, q0.z)) * rn;
            float z1 = (ft - q1.x) * q1.y;
            float p1 = __expf(fmaf(z1, -0.5f * z1, q1.z)) * rn;
            wo[(size_t)l * T] = p0;
            wo[(size_t)(l + 1) * T] = p1;
            pkw[jj] = (u32)f2bf(p0) | ((u32)f2bf(p1) << 16);
        }
        uint4 pk = make_uint4(pkw[0], pkw[1], pkw[2], pkw[3]);
        ((uint4*)wrow)[c] = pk;
    }
}

// ---------------- K6: batched GEMM  out[b,t,e] = sum_l WtT[b,t,l] * XcT[b,e,l] ----------------
__global__ __launch_bounds__(256) void k_gemm(const u16* __restrict__ WtT,
                                              const u16* __restrict__ XcT,
                                              float* __restrict__ out, int T, int Tp) {
    __shared__ u16 At[2][128][32];
    __shared__ u16 Bt[2][128][32];
    int b = blockIdx.z;
    int t0 = blockIdx.y * 128;
    int e0 = blockIdx.x * 128;
    int tid = threadIdx.x;
    int lane = tid & 63, wid = tid >> 6;
    int wm = wid >> 1, wn = wid & 1;
    const u16* Ab = WtT + (size_t)b * Tp * NL;
    const u16* Bb = XcT + (size_t)b * NE * NL;

    int srow = wid * 32 + (lane >> 2);
    int skc = (lane & 3) * 8;

    f32x4 acc[4][4];
    #pragma unroll
    for (int m = 0; m < 4; m++)
        #pragma unroll
        for (int n = 0; n < 4; n++)
            #pragma unroll
            for (int k = 0; k < 4; k++) acc[m][n][k] = 0.0f;

    auto stage = [&](int buf, int ks) {
        int l0 = ks * 32;
        const u16* ga = Ab + (size_t)(t0 + srow) * NL + l0 + skc;
        gload_lds16(ga, &At[buf][wid * 32][0]);
        gload_lds16(ga + 16 * NL, &At[buf][wid * 32 + 16][0]);
        const u16* gb = Bb + (size_t)(e0 + srow) * NL + l0 + skc;
        gload_lds16(gb, &Bt[buf][wid * 32][0]);
        gload_lds16(gb + 16 * NL, &Bt[buf][wid * 32 + 16][0]);
    };

    stage(0, 0);
    int fr = lane & 15, fk = (lane >> 4) * 8;
    for (int ks = 0; ks < 16; ++ks) {
        __syncthreads();  // staged buf[ks&1] visible; prior ds_reads drained
        if (ks + 1 < 16) stage((ks + 1) & 1, ks + 1);
        int buf = ks & 1;
        short8 a[4], bb[4];
        #pragma unroll
        for (int m = 0; m < 4; m++)
            a[m] = *(const short8*)&At[buf][wm * 64 + m * 16 + fr][fk];
        #pragma unroll
        for (int n = 0; n < 4; n++)
            bb[n] = *(const short8*)&Bt[buf][wn * 64 + n * 16 + fr][fk];
        #pragma unroll
        for (int m = 0; m < 4; m++)
            #pragma unroll
            for (int n = 0; n < 4; n++)
                acc[m][n] = __builtin_amdgcn_mfma_f32_16x16x32_bf16(a[m], bb[n], acc[m][n], 0, 0, 0);
    }

    int r4 = (lane >> 4) * 4;
    #pragma unroll
    for (int m = 0; m < 4; m++) {
        int tb = t0 + wm * 64 + m * 16 + r4;
        #pragma unroll
        for (int j = 0; j < 4; j++) {
            int t = tb + j;
            if (t < T) {
                float* orow = out + ((size_t)b * T + t) * NE + e0 + wn * 64 + (lane & 15);
                #pragma unroll
                for (int n = 0; n < 4; n++) orow[n * 16] = acc[m][n][j];
            }
        }
    }
}

extern "C" void kernel_launch(void* const* d_in, const int* in_sizes, int n_in,
                              void* d_out, int out_size, void* d_ws, size_t ws_size,
                              hipStream_t stream) {
    const float* x      = (const float*)d_in[0];
    const float* df     = (const float*)d_in[1];
    const int*   dint   = (const int*)d_in[2];
    const float* en     = (const float*)d_in[3];
    const float* pt     = (const float*)d_in[4];
    const int*   lens   = (const int*)d_in[5];
    const float* frames = (const float*)d_in[6];
    const float* wd     = (const float*)d_in[7];
    const float* bd     = (const float*)d_in[8];
    const float* wn     = (const float*)d_in[9];
    const float* bn     = (const float*)d_in[10];
    const float* wq     = (const float*)d_in[11];
    const float* bq     = (const float*)d_in[12];
    const float* wproj  = (const float*)d_in[13];
    const float* bproj  = (const float*)d_in[14];

    int T = in_sizes[6];
    int Tp = ((T + 127) / 128) * 128;

    char* ws = (char*)d_ws;
    float* taps    = (float*)(ws);                  // 10 floats
    float* means   = (float*)(ws + 256);            // B*L
    float* inv_std = (float*)(ws + 256 + 32768);    // B*L
    float* Aarr    = (float*)(ws + 256 + 65536);    // B*L
    u16*   XcT     = (u16*)(ws + 98560);            // B*E*L bf16 = 8.39 MB
    u16*   WtT     = (u16*)(ws + 98560 + 8388608);  // B*Tp*L bf16

    float* out_up = (float*)d_out;                       // (B,T,E)
    float* out_w  = out_up + (size_t)NB * T * NE;        // (B,L,T)

    k_taps<<<dim3(1), dim3(512), 0, stream>>>(wproj, wd, bd, wn, bn, wq, bq, bproj, taps);
    k_means<<<dim3(NB), dim3(512), 0, stream>>>(dint, means);
    k_ranges<<<dim3(NB * NL / 8), dim3(512), 0, stream>>>(x, df, en, pt, lens, taps, wproj,
                                                          inv_std, Aarr);
    k_xc<<<dim3(8, 8, NB), dim3(256), 0, stream>>>(x, en, pt, wn, bn, wq, bq, XcT);
    int nb = (Tp + 255) / 256;
    k_weights<<<dim3(nb, NB), dim3(256), 0, stream>>>(frames, means, inv_std, Aarr,
                                                      out_w, WtT, T, Tp);
    k_gemm<<<dim3(4, Tp / 128, NB), dim3(256), 0, stream>>>(WtT, XcT, out_up, T, Tp);
}

// Round 2
// 99.989 us; speedup vs baseline: 1.1361x; 1.1361x over previous
//
#include <hip/hip_runtime.h>

typedef unsigned short u16;
typedef unsigned int u32;
typedef __attribute__((ext_vector_type(8))) short short8;
typedef __attribute__((ext_vector_type(4))) float f32x4;

#define LOG_SQRT_2PI 0.9189385332046727f
#define NB 16
#define NL 512
#define NE 512
#define ZWIN 20.0f
#define MAXTB 32

__device__ __forceinline__ u16 f2bf(float x) {
    u32 u = __builtin_bit_cast(u32, x);
    u += 0x7fffu + ((u >> 16) & 1u);
    return (u16)(u >> 16);
}

__device__ __forceinline__ void gload_lds16(const u16* g, u16* l) {
    __builtin_amdgcn_global_load_lds(
        (__attribute__((address_space(1))) void*)(u16*)g,
        (__attribute__((address_space(3))) void*)l,
        16, 0, 0);
}

// ---------------- K1: effective duration taps through projection ----------------
// taps[0..2] = sum_e wproj[e]*w_dur[e,k]; taps[3] = sum_e wproj[e]*b_dur[e] + b_proj
__global__ void k_taps(const float* __restrict__ wproj, const float* __restrict__ wd,
                       const float* __restrict__ bd, const float* __restrict__ bproj,
                       float* __restrict__ taps) {
    int e = threadIdx.x;  // 512
    float wp = wproj[e];
    float v[4] = {wp * wd[e * 3 + 0], wp * wd[e * 3 + 1], wp * wd[e * 3 + 2], wp * bd[e]};
    __shared__ float red[4][8];
    int lane = e & 63, w = e >> 6;
    #pragma unroll
    for (int i = 0; i < 4; i++) {
        float s = v[i];
        for (int m = 32; m; m >>= 1) s += __shfl_xor(s, m);
        if (lane == 0) red[i][w] = s;
    }
    __syncthreads();
    if (e < 4) {
        float s = 0.f;
        for (int w2 = 0; w2 < 8; w2++) s += red[e][w2];
        if (e == 3) s += bproj[0];
        taps[e] = s;
    }
}

// ---------------- K2: means via inclusive cumsum; zero dot buffer ----------------
__global__ void k_means(const int* __restrict__ dint, float* __restrict__ means,
                        float* __restrict__ dotbuf) {
    int b = blockIdx.x, l = threadIdx.x;  // 512 threads
    __shared__ float s[NL];
    float d = (float)dint[b * NL + l];
    s[l] = d;
    dotbuf[b * NL + l] = 0.0f;
    __syncthreads();
    for (int off = 1; off < NL; off <<= 1) {
        float v = (l >= off) ? s[l - off] : 0.0f;
        __syncthreads();
        s[l] += v;
        __syncthreads();
    }
    means[b * NL + l] = s[l] - 0.5f * d;
}

// ---------------- K3: xc = x + conv(nrg) + conv(pitch) -> XcT[b][e][l] bf16,
//                  plus partial dot(xc, wproj) accumulated to dotbuf ----------------
__global__ void k_xc(const float* __restrict__ x, const float* __restrict__ en,
                     const float* __restrict__ pt,
                     const float* __restrict__ wn, const float* __restrict__ bn,
                     const float* __restrict__ wq, const float* __restrict__ bq,
                     const float* __restrict__ wproj,
                     u16* __restrict__ XcT, float* __restrict__ dotbuf) {
    __shared__ u16 tile[64][66];
    int b = blockIdx.z;
    int l0 = blockIdx.y * 64, e0 = blockIdx.x * 64;
    int tid = threadIdx.x;         // 256
    int lr = tid >> 6, c = tid & 63;
    int e = e0 + c;
    float wn0 = wn[e * 3], wn1 = wn[e * 3 + 1], wn2 = wn[e * 3 + 2];
    float wq0 = wq[e * 3], wq1 = wq[e * 3 + 1], wq2 = wq[e * 3 + 2];
    float bias = bn[e] + bq[e];
    float wp = wproj[e];
    #pragma unroll 4
    for (int it = 0; it < 16; ++it) {
        int ll = lr * 16 + it;
        int l = l0 + ll;
        int base = b * NL;
        float em1 = (l > 0)   ? en[base + l - 1] : 0.f;
        float ev  = en[base + l];
        float ep1 = (l < 511) ? en[base + l + 1] : 0.f;
        float pm1 = (l > 0)   ? pt[base + l - 1] : 0.f;
        float pv  = pt[base + l];
        float pp1 = (l < 511) ? pt[base + l + 1] : 0.f;
        float v = x[((size_t)(base + l)) * NE + e]
                + wn0 * em1 + wn1 * ev + wn2 * ep1
                + wq0 * pm1 + wq1 * pv + wq2 * pp1 + bias;
        tile[ll][c] = f2bf(v);
        float s = v * wp;
        for (int m = 32; m; m >>= 1) s += __shfl_xor(s, m);
        if (c == 0) atomicAdd(&dotbuf[base + l], s);
    }
    __syncthreads();
    #pragma unroll 4
    for (int it = 0; it < 16; ++it) {
        int eo = lr + 4 * it;  // 0..63
        XcT[((size_t)b * NE + (e0 + eo)) * NL + l0 + c] = tile[c][eo];
    }
}

// ---------------- K4: ranges -> inv_std, A; per-(b,tblock) l-window table ----------------
__global__ void k_rw(const float* __restrict__ df, const int* __restrict__ lens,
                     const float* __restrict__ taps, const float* __restrict__ dotbuf,
                     const float* __restrict__ means,
                     float* __restrict__ inv_std, float* __restrict__ Aarr,
                     int2* __restrict__ win, int ntb) {
    int b = blockIdx.x, l = threadIdx.x;  // 512 threads
    __shared__ int slo[MAXTB], shi[MAXTB];
    if (l < ntb) { slo[l] = NL; shi[l] = -1; }
    __syncthreads();
    int base = b * NL;
    float dm1 = (l > 0)   ? df[base + l - 1] : 0.f;
    float d0  = df[base + l];
    float dp1 = (l < 511) ? df[base + l + 1] : 0.f;
    float lin = dotbuf[base + l] + taps[3]
              + taps[0] * dm1 + taps[1] * d0 + taps[2] * dp1;
    float r = (lin > 20.f) ? lin : log1pf(expf(lin));
    bool pad = (l >= lens[b]);
    if (pad) r = 1.0f;
    float sd = fmaxf(r, 0.001f);
    inv_std[base + l] = 1.0f / sd;
    Aarr[base + l] = pad ? -1e30f : (-logf(sd) - LOG_SQRT_2PI);
    if (!pad) {
        float m = means[base + l];
        float fl = m - ZWIN * sd - 1.0f;
        float fh = m + ZWIN * sd + 1.0f;
        for (int tb = 0; tb < ntb; ++tb) {
            float t_lo = tb * 128.0f + 0.5f, t_hi = tb * 128.0f + 127.5f;
            if (fl <= t_hi && fh >= t_lo) {
                atomicMin(&slo[tb], l);
                atomicMax(&shi[tb], l);
            }
        }
    }
    __syncthreads();
    if (l < ntb) win[b * MAXTB + l] = make_int2(slo[l], shi[l]);
}

// ---------------- K5: weights (f32 out) + WtT[b][t][l] bf16, zero-padded rows ----------------
__global__ void k_weights(const float* __restrict__ frames, const float* __restrict__ means,
                          const float* __restrict__ inv_std, const float* __restrict__ Aarr,
                          float* __restrict__ wout, u16* __restrict__ WtT, int T, int Tp) {
    int b = blockIdx.y;
    __shared__ float4 sq[NL];  // {mean, inv_std, A, 0}
    for (int i = threadIdx.x; i < NL; i += 256) {
        sq[i] = make_float4(means[b * NL + i], inv_std[b * NL + i], Aarr[b * NL + i], 0.f);
    }
    __syncthreads();
    int t = blockIdx.x * 256 + threadIdx.x;
    if (t >= Tp) return;
    u16* wrow = WtT + ((size_t)(b * Tp + t)) * NL;
    if (t >= T) {
        uint4 z = make_uint4(0, 0, 0, 0);
        #pragma unroll 4
        for (int i = 0; i < 64; i++) ((uint4*)wrow)[i] = z;
        return;
    }
    float ft = frames[t];
    float sum = 0.f;
    #pragma unroll 4
    for (int l = 0; l < NL; ++l) {
        float4 q = sq[l];
        float z = (ft - q.x) * q.y;
        sum += __expf(fmaf(z, -0.5f * z, q.z));
    }
    float rn = 1.0f / (sum + 1e-20f);
    float* wo = wout + (size_t)b * NL * T + t;
    for (int c = 0; c < 64; c++) {
        u32 pkw[4];
        #pragma unroll
        for (int jj = 0; jj < 4; jj++) {
            int l = c * 8 + jj * 2;
            float4 q0 = sq[l], q1 = sq[l + 1];
            float z0 = (ft - q0.x) * q0.y;
            float p0 = __expf(fmaf(z0, -0.5f * z0, q0.z)) * rn;
            float z1 = (ft - q1.x) * q1.y;
            float p1 = __expf(fmaf(z1, -0.5f * z1, q1.z)) * rn;
            wo[(size_t)l * T] = p0;
            wo[(size_t)(l + 1) * T] = p1;
            pkw[jj] = (u32)f2bf(p0) | ((u32)f2bf(p1) << 16);
        }
        uint4 pk = make_uint4(pkw[0], pkw[1], pkw[2], pkw[3]);
        ((uint4*)wrow)[c] = pk;
    }
}

// ---------------- K6: banded batched GEMM  out[b,t,e] = sum_{l in win} WtT * XcT ----------------
__global__ __launch_bounds__(256) void k_gemm(const u16* __restrict__ WtT,
                                              const u16* __restrict__ XcT,
                                              const int2* __restrict__ win,
                                              float* __restrict__ out, int T, int Tp) {
    __shared__ u16 At[2][128][32];
    __shared__ u16 Bt[2][128][32];
    int b = blockIdx.z;
    int t0 = blockIdx.y * 128;
    int e0 = blockIdx.x * 128;
    int tid = threadIdx.x;
    int lane = tid & 63, wid = tid >> 6;
    int wm = wid >> 1, wn = wid & 1;
    const u16* Ab = WtT + (size_t)b * Tp * NL;
    const u16* Bb = XcT + (size_t)b * NE * NL;

    int2 w = win[b * MAXTB + blockIdx.y];
    int ks0 = 0, nst = 0;
    if (w.x <= w.y) { ks0 = w.x >> 5; nst = (w.y >> 5) - ks0 + 1; }

    int srow = wid * 32 + (lane >> 2);
    int skc = (lane & 3) * 8;

    f32x4 acc[4][4];
    #pragma unroll
    for (int m = 0; m < 4; m++)
        #pragma unroll
        for (int n = 0; n < 4; n++)
            #pragma unroll
            for (int k = 0; k < 4; k++) acc[m][n][k] = 0.0f;

    auto stage = [&](int buf, int ks) {
        int l0 = ks * 32;
        const u16* ga = Ab + (size_t)(t0 + srow) * NL + l0 + skc;
        gload_lds16(ga, &At[buf][wid * 32][0]);
        gload_lds16(ga + 16 * NL, &At[buf][wid * 32 + 16][0]);
        const u16* gb = Bb + (size_t)(e0 + srow) * NL + l0 + skc;
        gload_lds16(gb, &Bt[buf][wid * 32][0]);
        gload_lds16(gb + 16 * NL, &Bt[buf][wid * 32 + 16][0]);
    };

    int fr = lane & 15, fk = (lane >> 4) * 8;
    if (nst > 0) {
        stage(0, ks0);
        for (int s = 0; s < nst; ++s) {
            __syncthreads();  // staged buf[s&1] visible; prior ds_reads drained
            if (s + 1 < nst) stage((s + 1) & 1, ks0 + s + 1);
            int buf = s & 1;
            short8 a[4], bb[4];
            #pragma unroll
            for (int m = 0; m < 4; m++)
                a[m] = *(const short8*)&At[buf][wm * 64 + m * 16 + fr][fk];
            #pragma unroll
            for (int n = 0; n < 4; n++)
                bb[n] = *(const short8*)&Bt[buf][wn * 64 + n * 16 + fr][fk];
            #pragma unroll
            for (int m = 0; m < 4; m++)
                #pragma unroll
                for (int n = 0; n < 4; n++)
                    acc[m][n] = __builtin_amdgcn_mfma_f32_16x16x32_bf16(a[m], bb[n], acc[m][n], 0, 0, 0);
        }
    }

    int r4 = (lane >> 4) * 4;
    #pragma unroll
    for (int m = 0; m < 4; m++) {
        int tb = t0 + wm * 64 + m * 16 + r4;
        #pragma unroll
        for (int j = 0; j < 4; j++) {
            int t = tb + j;
            if (t < T) {
                float* orow = out + ((size_t)b * T + t) * NE + e0 + wn * 64 + (lane & 15);
                #pragma unroll
                for (int n = 0; n < 4; n++) orow[n * 16] = acc[m][n][j];
            }
        }
    }
}

extern "C" void kernel_launch(void* const* d_in, const int* in_sizes, int n_in,
                              void* d_out, int out_size, void* d_ws, size_t ws_size,
                              hipStream_t stream) {
    const float* x      = (const float*)d_in[0];
    const float* df     = (const float*)d_in[1];
    const int*   dint   = (const int*)d_in[2];
    const float* en     = (const float*)d_in[3];
    const float* pt     = (const float*)d_in[4];
    const int*   lens   = (const int*)d_in[5];
    const float* frames = (const float*)d_in[6];
    const float* wd     = (const float*)d_in[7];
    const float* bd     = (const float*)d_in[8];
    const float* wn     = (const float*)d_in[9];
    const float* bn     = (const float*)d_in[10];
    const float* wq     = (const float*)d_in[11];
    const float* bq     = (const float*)d_in[12];
    const float* wproj  = (const float*)d_in[13];
    const float* bproj  = (const float*)d_in[14];

    int T = in_sizes[6];
    int Tp = ((T + 127) / 128) * 128;
    int ntb = Tp / 128;  // <= 32 since T <= 8*512

    char* ws = (char*)d_ws;
    float* taps    = (float*)(ws);                          // 4 floats
    float* means   = (float*)(ws + 256);                    // B*L
    float* inv_std = (float*)(ws + 256 + 32768);            // B*L
    float* Aarr    = (float*)(ws + 256 + 65536);            // B*L
    float* dotbuf  = (float*)(ws + 256 + 98304);            // B*L
    int2*  win     = (int2*)(ws + 256 + 131072);            // B*MAXTB
    u16*   XcT     = (u16*)(ws + 256 + 131072 + 4096);      // B*E*L bf16 = 8.39 MB
    u16*   WtT     = (u16*)(ws + 256 + 131072 + 4096 + 8388608);  // B*Tp*L bf16

    float* out_up = (float*)d_out;                 // (B,T,E)
    float* out_w  = out_up + (size_t)NB * T * NE;  // (B,L,T)

    k_taps<<<dim3(1), dim3(512), 0, stream>>>(wproj, wd, bd, bproj, taps);
    k_means<<<dim3(NB), dim3(512), 0, stream>>>(dint, means, dotbuf);
    k_xc<<<dim3(8, 8, NB), dim3(256), 0, stream>>>(x, en, pt, wn, bn, wq, bq, wproj,
                                                   XcT, dotbuf);
    k_rw<<<dim3(NB), dim3(512), 0, stream>>>(df, lens, taps, dotbuf, means,
                                             inv_std, Aarr, win, ntb);
    int nb = (Tp + 255) / 256;
    k_weights<<<dim3(nb, NB), dim3(256), 0, stream>>>(frames, means, inv_std, Aarr,
                                                      out_w, WtT, T, Tp);
    k_gemm<<<dim3(4, ntb, NB), dim3(256), 0, stream>>>(WtT, XcT, win, out_up, T, Tp);
}

// Round 3
// 83.363 us; speedup vs baseline: 1.3627x; 1.1994x over previous
//
#include <hip/hip_runtime.h>

typedef unsigned short u16;
typedef unsigned int u32;
typedef __attribute__((ext_vector_type(8))) short short8;
typedef __attribute__((ext_vector_type(4))) float f32x4;

#define LOG_SQRT_2PI 0.9189385332046727f
#define NB 16
#define NL 512
#define NE 512
#define ZWIN 20.0f
#define MAXTB 32

__device__ __forceinline__ u16 f2bf(float x) {
    u32 u = __builtin_bit_cast(u32, x);
    u += 0x7fffu + ((u >> 16) & 1u);
    return (u16)(u >> 16);
}

__device__ __forceinline__ void gload_lds16(const u16* g, u16* l) {
    __builtin_amdgcn_global_load_lds(
        (__attribute__((address_space(1))) void*)(u16*)g,
        (__attribute__((address_space(3))) void*)l,
        16, 0, 0);
}

// ---------------- K1: effective duration taps through projection ----------------
__global__ void k_taps(const float* __restrict__ wproj, const float* __restrict__ wd,
                       const float* __restrict__ bd, const float* __restrict__ bproj,
                       float* __restrict__ taps) {
    int e = threadIdx.x;  // 512
    float wp = wproj[e];
    float v[4] = {wp * wd[e * 3 + 0], wp * wd[e * 3 + 1], wp * wd[e * 3 + 2], wp * bd[e]};
    __shared__ float red[4][8];
    int lane = e & 63, w = e >> 6;
    #pragma unroll
    for (int i = 0; i < 4; i++) {
        float s = v[i];
        for (int m = 32; m; m >>= 1) s += __shfl_xor(s, m);
        if (lane == 0) red[i][w] = s;
    }
    __syncthreads();
    if (e < 4) {
        float s = 0.f;
        for (int w2 = 0; w2 < 8; w2++) s += red[e][w2];
        if (e == 3) s += bproj[0];
        taps[e] = s;
    }
}

// ---------------- K2: means via inclusive cumsum; zero dot buffer ----------------
__global__ void k_means(const int* __restrict__ dint, float* __restrict__ means,
                        float* __restrict__ dotbuf) {
    int b = blockIdx.x, l = threadIdx.x;  // 512 threads
    __shared__ float s[NL];
    float d = (float)dint[b * NL + l];
    s[l] = d;
    dotbuf[b * NL + l] = 0.0f;
    __syncthreads();
    for (int off = 1; off < NL; off <<= 1) {
        float v = (l >= off) ? s[l - off] : 0.0f;
        __syncthreads();
        s[l] += v;
        __syncthreads();
    }
    means[b * NL + l] = s[l] - 0.5f * d;
}

// ---------------- K3: xc -> XcT[b][e][l] bf16 + partial dot(xc, wproj) ----------------
__global__ void k_xc(const float* __restrict__ x, const float* __restrict__ en,
                     const float* __restrict__ pt,
                     const float* __restrict__ wn, const float* __restrict__ bn,
                     const float* __restrict__ wq, const float* __restrict__ bq,
                     const float* __restrict__ wproj,
                     u16* __restrict__ XcT, float* __restrict__ dotbuf) {
    __shared__ u16 tile[64][66];
    int b = blockIdx.z;
    int l0 = blockIdx.y * 64, e0 = blockIdx.x * 64;
    int tid = threadIdx.x;         // 256
    int lr = tid >> 6, c = tid & 63;
    int e = e0 + c;
    float wn0 = wn[e * 3], wn1 = wn[e * 3 + 1], wn2 = wn[e * 3 + 2];
    float wq0 = wq[e * 3], wq1 = wq[e * 3 + 1], wq2 = wq[e * 3 + 2];
    float bias = bn[e] + bq[e];
    float wp = wproj[e];
    #pragma unroll 4
    for (int it = 0; it < 16; ++it) {
        int ll = lr * 16 + it;
        int l = l0 + ll;
        int base = b * NL;
        float em1 = (l > 0)   ? en[base + l - 1] : 0.f;
        float ev  = en[base + l];
        float ep1 = (l < 511) ? en[base + l + 1] : 0.f;
        float pm1 = (l > 0)   ? pt[base + l - 1] : 0.f;
        float pv  = pt[base + l];
        float pp1 = (l < 511) ? pt[base + l + 1] : 0.f;
        float v = x[((size_t)(base + l)) * NE + e]
                + wn0 * em1 + wn1 * ev + wn2 * ep1
                + wq0 * pm1 + wq1 * pv + wq2 * pp1 + bias;
        tile[ll][c] = f2bf(v);
        float s = v * wp;
        for (int m = 32; m; m >>= 1) s += __shfl_xor(s, m);
        if (c == 0) atomicAdd(&dotbuf[base + l], s);
    }
    __syncthreads();
    #pragma unroll 4
    for (int it = 0; it < 16; ++it) {
        int eo = lr + 4 * it;  // 0..63
        XcT[((size_t)b * NE + (e0 + eo)) * NL + l0 + c] = tile[c][eo];
    }
}

// ---------------- K4: ranges -> inv_std, A; per-(b,tblock) l-window table ----------------
__global__ void k_rw(const float* __restrict__ df, const int* __restrict__ lens,
                     const float* __restrict__ taps, const float* __restrict__ dotbuf,
                     const float* __restrict__ means,
                     float* __restrict__ inv_std, float* __restrict__ Aarr,
                     int2* __restrict__ win, int ntb) {
    int b = blockIdx.x, l = threadIdx.x;  // 512 threads
    __shared__ int slo[MAXTB], shi[MAXTB];
    if (l < ntb) { slo[l] = NL; shi[l] = -1; }
    __syncthreads();
    int base = b * NL;
    float dm1 = (l > 0)   ? df[base + l - 1] : 0.f;
    float d0  = df[base + l];
    float dp1 = (l < 511) ? df[base + l + 1] : 0.f;
    float lin = dotbuf[base + l] + taps[3]
              + taps[0] * dm1 + taps[1] * d0 + taps[2] * dp1;
    float r = (lin > 20.f) ? lin : log1pf(expf(lin));
    bool pad = (l >= lens[b]);
    if (pad) r = 1.0f;
    float sd = fmaxf(r, 0.001f);
    inv_std[base + l] = 1.0f / sd;
    Aarr[base + l] = pad ? -1e30f : (-logf(sd) - LOG_SQRT_2PI);
    if (!pad) {
        float m = means[base + l];
        float fl = m - ZWIN * sd - 1.0f;
        float fh = m + ZWIN * sd + 1.0f;
        for (int tb = 0; tb < ntb; ++tb) {
            float t_lo = tb * 128.0f + 0.5f, t_hi = tb * 128.0f + 127.5f;
            if (fl <= t_hi && fh >= t_lo) {
                atomicMin(&slo[tb], l);
                atomicMax(&shi[tb], l);
            }
        }
    }
    __syncthreads();
    if (l < ntb) win[b * MAXTB + l] = make_int2(slo[l], shi[l]);
}

// ---------------- K5: rn[b,t] = 1/(sum_band p + eps); stream out_w (zeros + band) ----------------
__global__ void k_wout(const float* __restrict__ frames, const float* __restrict__ means,
                       const float* __restrict__ inv_std, const float* __restrict__ Aarr,
                       const int2* __restrict__ win,
                       float* __restrict__ rn, float* __restrict__ wout, int T, int Tpad) {
    int b = blockIdx.y, tb = blockIdx.x;
    int t0 = tb * 128;
    int tid = threadIdx.x;  // 128
    __shared__ float4 sq[NL];
    for (int i = tid; i < NL; i += 128)
        sq[i] = make_float4(means[b * NL + i], inv_std[b * NL + i], Aarr[b * NL + i], 0.f);
    int t = t0 + tid;
    float ft = (t < T) ? frames[t] : -1e9f;
    __syncthreads();
    int2 w = win[b * MAXTB + tb];
    float s0 = 0.f, s1 = 0.f;
    int l = w.x;
    for (; l + 1 <= w.y; l += 2) {
        float4 q0 = sq[l], q1 = sq[l + 1];
        float z0 = (ft - q0.x) * q0.y;
        s0 += __expf(fmaf(z0, -0.5f * z0, q0.z));
        float z1 = (ft - q1.x) * q1.y;
        s1 += __expf(fmaf(z1, -0.5f * z1, q1.z));
    }
    if (l == w.y) {
        float4 q = sq[l];
        float z = (ft - q.x) * q.y;
        s0 += __expf(fmaf(z, -0.5f * z, q.z));
    }
    float r = (t < T) ? 1.0f / (s0 + s1 + 1e-20f) : 0.0f;
    rn[b * Tpad + t] = r;
    if (t < T) {
        float* dst = wout + (size_t)b * NL * T + t;
        #pragma unroll 4
        for (int ll = 0; ll < NL; ++ll) {
            float v = 0.f;
            if (ll >= w.x && ll <= w.y) {  // wave-uniform branch
                float4 q = sq[ll];
                float z = (ft - q.x) * q.y;
                v = __expf(fmaf(z, -0.5f * z, q.z)) * r;
            }
            dst[(size_t)ll * T] = v;
        }
    }
}

// ---------------- K6: banded GEMM, A-tile (weights bf16) computed in-kernel ----------------
__global__ __launch_bounds__(256) void k_gemm(const u16* __restrict__ XcT,
                                              const float* __restrict__ frames,
                                              const float* __restrict__ rn,
                                              const float* __restrict__ means,
                                              const float* __restrict__ inv_std,
                                              const float* __restrict__ Aarr,
                                              const int2* __restrict__ win,
                                              float* __restrict__ out, int T, int Tpad) {
    __shared__ float4 sq[NL];
    __shared__ u16 At[2][128][32];
    __shared__ u16 Bt[2][128][32];
    int b = blockIdx.z;
    int t0 = blockIdx.y * 128;
    int e0 = blockIdx.x * 128;
    int tid = threadIdx.x;
    int lane = tid & 63, wid = tid >> 6;
    int wm = wid >> 1, wn = wid & 1;
    const u16* Bb = XcT + (size_t)b * NE * NL;

    for (int i = tid; i < NL; i += 256)
        sq[i] = make_float4(means[b * NL + i], inv_std[b * NL + i], Aarr[b * NL + i], 0.f);

    int ta = tid >> 1;        // A-row (t offset) this thread fills
    int ha = (tid & 1) * 16;  // which 16-col half
    int tg = t0 + ta;
    float ft = (tg < T) ? frames[tg] : -1e9f;
    float rv = rn[b * Tpad + t0 + ta];

    int2 w = win[b * MAXTB + blockIdx.y];
    int ks0 = 0, nst = 0;
    if (w.x <= w.y) { ks0 = w.x >> 5; nst = (w.y >> 5) - ks0 + 1; }

    int srow = wid * 32 + (lane >> 2);
    int skc = (lane & 3) * 8;

    f32x4 acc[4][4];
    #pragma unroll
    for (int m = 0; m < 4; m++)
        #pragma unroll
        for (int n = 0; n < 4; n++)
            #pragma unroll
            for (int k = 0; k < 4; k++) acc[m][n][k] = 0.0f;

    auto stage = [&](int buf, int ks) {
        int l0 = ks * 32;
        const u16* gb = Bb + (size_t)(e0 + srow) * NL + l0 + skc;
        gload_lds16(gb, &Bt[buf][wid * 32][0]);
        gload_lds16(gb + 16 * NL, &Bt[buf][wid * 32 + 16][0]);
        u32 pk[8];
        #pragma unroll
        for (int jj = 0; jj < 8; ++jj) {
            float4 q0 = sq[l0 + ha + jj * 2];
            float4 q1 = sq[l0 + ha + jj * 2 + 1];
            float z0 = (ft - q0.x) * q0.y;
            float p0 = __expf(fmaf(z0, -0.5f * z0, q0.z)) * rv;
            float z1 = (ft - q1.x) * q1.y;
            float p1 = __expf(fmaf(z1, -0.5f * z1, q1.z)) * rv;
            pk[jj] = (u32)f2bf(p0) | ((u32)f2bf(p1) << 16);
        }
        *(uint4*)&At[buf][ta][ha]     = make_uint4(pk[0], pk[1], pk[2], pk[3]);
        *(uint4*)&At[buf][ta][ha + 8] = make_uint4(pk[4], pk[5], pk[6], pk[7]);
    };

    __syncthreads();  // sq visible before stage() uses it
    int fr = lane & 15, fk = (lane >> 4) * 8;
    if (nst > 0) {
        stage(0, ks0);
        for (int s = 0; s < nst; ++s) {
            __syncthreads();  // buf[s&1] (ds_writes + gload_lds) visible
            if (s + 1 < nst) stage((s + 1) & 1, ks0 + s + 1);
            int buf = s & 1;
            short8 a[4], bb[4];
            #pragma unroll
            for (int m = 0; m < 4; m++)
                a[m] = *(const short8*)&At[buf][wm * 64 + m * 16 + fr][fk];
            #pragma unroll
            for (int n = 0; n < 4; n++)
                bb[n] = *(const short8*)&Bt[buf][wn * 64 + n * 16 + fr][fk];
            #pragma unroll
            for (int m = 0; m < 4; m++)
                #pragma unroll
                for (int n = 0; n < 4; n++)
                    acc[m][n] = __builtin_amdgcn_mfma_f32_16x16x32_bf16(a[m], bb[n], acc[m][n], 0, 0, 0);
        }
    }

    int r4 = (lane >> 4) * 4;
    #pragma unroll
    for (int m = 0; m < 4; m++) {
        int tb2 = t0 + wm * 64 + m * 16 + r4;
        #pragma unroll
        for (int j = 0; j < 4; j++) {
            int t = tb2 + j;
            if (t < T) {
                float* orow = out + ((size_t)b * T + t) * NE + e0 + wn * 64 + (lane & 15);
                #pragma unroll
                for (int n = 0; n < 4; n++) orow[n * 16] = acc[m][n][j];
            }
        }
    }
}

extern "C" void kernel_launch(void* const* d_in, const int* in_sizes, int n_in,
                              void* d_out, int out_size, void* d_ws, size_t ws_size,
                              hipStream_t stream) {
    const float* x      = (const float*)d_in[0];
    const float* df     = (const float*)d_in[1];
    const int*   dint   = (const int*)d_in[2];
    const float* en     = (const float*)d_in[3];
    const float* pt     = (const float*)d_in[4];
    const int*   lens   = (const int*)d_in[5];
    const float* frames = (const float*)d_in[6];
    const float* wd     = (const float*)d_in[7];
    const float* bd     = (const float*)d_in[8];
    const float* wn     = (const float*)d_in[9];
    const float* bn     = (const float*)d_in[10];
    const float* wq     = (const float*)d_in[11];
    const float* bq     = (const float*)d_in[12];
    const float* wproj  = (const float*)d_in[13];
    const float* bproj  = (const float*)d_in[14];

    int T = in_sizes[6];
    int ntb = (T + 127) / 128;   // <= 32
    int Tpad = ntb * 128;

    char* ws = (char*)d_ws;
    float* taps    = (float*)(ws);             // 4 floats (256 B slot)
    float* means   = (float*)(ws + 256);       // B*L
    float* inv_std = (float*)(ws + 33024);     // B*L
    float* Aarr    = (float*)(ws + 65792);     // B*L
    float* dotbuf  = (float*)(ws + 98560);     // B*L
    int2*  win     = (int2*)(ws + 131328);     // B*MAXTB
    float* rn      = (float*)(ws + 135424);    // B*Tpad (<= 256 KB)
    u16*   XcT     = (u16*)(ws + 397568);      // B*E*L bf16 = 8.39 MB

    float* out_up = (float*)d_out;                 // (B,T,E)
    float* out_w  = out_up + (size_t)NB * T * NE;  // (B,L,T)

    k_taps<<<dim3(1), dim3(512), 0, stream>>>(wproj, wd, bd, bproj, taps);
    k_means<<<dim3(NB), dim3(512), 0, stream>>>(dint, means, dotbuf);
    k_xc<<<dim3(8, 8, NB), dim3(256), 0, stream>>>(x, en, pt, wn, bn, wq, bq, wproj,
                                                   XcT, dotbuf);
    k_rw<<<dim3(NB), dim3(512), 0, stream>>>(df, lens, taps, dotbuf, means,
                                             inv_std, Aarr, win, ntb);
    k_wout<<<dim3(ntb, NB), dim3(128), 0, stream>>>(frames, means, inv_std, Aarr, win,
                                                    rn, out_w, T, Tpad);
    k_gemm<<<dim3(4, ntb, NB), dim3(256), 0, stream>>>(XcT, frames, rn, means, inv_std,
                                                       Aarr, win, out_up, T, Tpad);
}